// Round 16
// baseline (180.313 us; speedup 1.0000x reference)
//
#include <hip/hip_runtime.h>
#include <hip/hip_bf16.h>

// Problem dims (fixed by reference)
#define BATCH 128
#define PIX   196
#define EDIM  2048
#define DDIM  512
#define ADIM  512
#define MTOT  (BATCH*PIX)   // 25088
#define BK    32
#define NK    (EDIM/BK)     // 64 K-tiles
#define BM    256
#define NSLC  2             // 2 N-slices of 256

typedef __attribute__((ext_vector_type(8))) short short8;
typedef __attribute__((ext_vector_type(4))) float f32x4;

__device__ __forceinline__ unsigned short f2bf(float f) {
    union { float f; unsigned int u; } c; c.f = f;
    unsigned int u = c.u;
    u += 0x7fffu + ((u >> 16) & 1u);   // round-to-nearest-even
    return (unsigned short)(u >> 16);
}

// HW cvt (v_cvt_pk_bf16_f32; RNE, matches f2bf)
__device__ __forceinline__ short8 cvt8(float4 a, float4 b) {
    short8 v;
    v[0] = (short)__bfloat16_as_ushort(__float2bfloat16(a.x));
    v[1] = (short)__bfloat16_as_ushort(__float2bfloat16(a.y));
    v[2] = (short)__bfloat16_as_ushort(__float2bfloat16(a.z));
    v[3] = (short)__bfloat16_as_ushort(__float2bfloat16(a.w));
    v[4] = (short)__bfloat16_as_ushort(__float2bfloat16(b.x));
    v[5] = (short)__bfloat16_as_ushort(__float2bfloat16(b.y));
    v[6] = (short)__bfloat16_as_ushort(__float2bfloat16(b.z));
    v[7] = (short)__bfloat16_as_ushort(__float2bfloat16(b.w));
    return v;
}

#define GLOAD16(gp, lp) __builtin_amdgcn_global_load_lds( \
    (const __attribute__((address_space(1))) void*)(gp),  \
    (__attribute__((address_space(3))) void*)(lp), 16, 0, 0)

#define MFMA16(a, b, c) __builtin_amdgcn_mfma_f32_16x16x32_bf16(a, b, c, 0, 0, 0)

// ---------------------------------------------------------------------------
// Kernel 0: pack W_enc [K=2048][A=512] fp32 into per-(kt,ns) 16KB images, bf16
// (VERBATIM round-10/11 pack — bench-verified twice). Image (kt,ns):
// 16B slot c (c=0..1023): jj=c>>6 (0..15), l=c&63; holds bf16 of
//   W_enc[kt*32 + (l>>4)*8 + d][ns*256 + jj*16 + (l&15)], d=0..7.
// gemm frag read = jj*1024 + lane*16 (lane-linear: 0 conflicts).
// ---------------------------------------------------------------------------
__global__ __launch_bounds__(256) void pack_wenc(const float* __restrict__ Wenc,
                                                 unsigned short* __restrict__ WTp) {
    __shared__ float f[32 * ADIM];   // 64 KB: rows k=kt*32..+31
    const int kt = blockIdx.x;
    const int tid = threadIdx.x;
    const float4* src = (const float4*)(Wenc + (size_t)kt * 32 * ADIM);
    float4* dst = (float4*)f;
    #pragma unroll
    for (int i = 0; i < 16; ++i)
        dst[tid + i * 256] = src[tid + i * 256];
    __syncthreads();
    for (int c2 = tid; c2 < 2048; c2 += 256) {
        int ns = c2 >> 10;
        int c  = c2 & 1023;
        int jj = c >> 6;
        int l  = c & 63;
        int n  = ns * 256 + jj * 16 + (l & 15);
        int k0 = (l >> 4) * 8;
        short8 v;
        #pragma unroll
        for (int d = 0; d < 8; ++d)
            v[d] = (short)f2bf(f[(k0 + d) * ADIM + n]);
        *(short8*)(WTp + (size_t)kt * 16384 + (size_t)c2 * 8) = v;
    }
}

// ---------------------------------------------------------------------------
// Kernel 1: bias[b][a] = sum_d dec[b][d]*Wdec[d][a] + b_dec[a] + b_enc[a]
// ---------------------------------------------------------------------------
__global__ __launch_bounds__(256) void bias_kernel(const float* __restrict__ dec,
                                                   const float* __restrict__ Wdec,
                                                   const float* __restrict__ b_enc,
                                                   const float* __restrict__ b_dec,
                                                   float* __restrict__ bias) {
    __shared__ float ds[4 * DDIM];
    const int b0 = blockIdx.x * 4;
    for (int i = threadIdx.x; i < 4 * DDIM; i += 256)
        ds[i] = dec[(size_t)b0 * DDIM + i];
    __syncthreads();
    const int a0 = threadIdx.x * 2;
    float acc0[4] = {0.f, 0.f, 0.f, 0.f};
    float acc1[4] = {0.f, 0.f, 0.f, 0.f};
    for (int d = 0; d < DDIM; d++) {
        float2 w = *(const float2*)&Wdec[(size_t)d * ADIM + a0];
        #pragma unroll
        for (int bi = 0; bi < 4; bi++) {
            float dv = ds[bi * DDIM + d];
            acc0[bi] += dv * w.x;
            acc1[bi] += dv * w.y;
        }
    }
    float be0 = b_enc[a0] + b_dec[a0];
    float be1 = b_enc[a0 + 1] + b_dec[a0 + 1];
    #pragma unroll
    for (int bi = 0; bi < 4; bi++) {
        bias[(size_t)(b0 + bi) * ADIM + a0]     = acc0[bi] + be0;
        bias[(size_t)(b0 + bi) * ADIM + a0 + 1] = acc1[bi] + be1;
    }
}

// ---------------------------------------------------------------------------
// Kernel 2: fused att1 GEMM + relu + dot(W_full) -> att_part[ns][m]
// 256M x 256N x 32K, 1024 thr / 16 waves (4M x 4N), wave tile 64x64.
// Grid 196 = 98 panels x 2 slices (r12-verified bijective XCD twin-swizzle).
// A: fp32 staged DIRECTLY via global_load_lds (no reg/cvt/ds_write path —
//    cvt happens at frag-read time, off the staging critical path).
//    LDS layout built so BOTH fp32 frag halves are lane*16-linear reads.
// B: r10-verified bf16 images via global_load_lds (wave-uniform dest).
// LDS 96 KB dbuf; one __syncthreads per K-tile; 4 waves/SIMD in one
// barrier domain give intra-block TLP; all LDS reads conflict-free.
// ---------------------------------------------------------------------------
__global__ __launch_bounds__(1024, 4) void gemm_att(const float* __restrict__ enc,
                                                    const unsigned short* __restrict__ WTp,
                                                    const float* __restrict__ bias,
                                                    const float* __restrict__ Wfull,
                                                    float* __restrict__ att_part) {
    __shared__ __align__(16) char ldsA[2][32768];   // fp32 A tiles 256x32
    __shared__ __align__(16) char ldsB[2][16384];   // bf16 B tiles 256x32

    const int tid  = threadIdx.x;
    const int lane = tid & 63;
    const int wid  = tid >> 6;          // 0..15
    const int wm   = wid >> 2;          // 0..3 (M quarter: 64 rows)
    const int wn   = wid & 3;           // 0..3 (N quarter: 64 cols)
    const int cif  = lane & 15;
    const int rgrp = lane >> 4;

    // XCD twin-swizzle (r12-verified for grid 196): twins 8 slots apart.
    const int raw = blockIdx.x;
    int g, ns;
    if (raw < 192) { g = (raw >> 4) * 8 + (raw & 7); ns = (raw >> 3) & 1; }
    else           { int r2 = raw - 192; g = 96 + (r2 >> 1); ns = r2 & 1; }
    const int m0 = g * BM;

    // A staging: wave w stages rows m0+w*16..+16. Two gloads per iter:
    //   g=0: lane l -> row w*16+(l&15), floats (l>>4)*8 + 0..3
    //   g=1: lane l -> row w*16+(l&15), floats (l>>4)*8 + 4..7
    // LDS: chunk w = 2KB at w*2048; g-half at +g*1024 (wave-uniform dest).
    // Frag read i (rows wm*64+i*16+cif, floats rgrp*8..+8):
    //   read1 = (wm*4+i)*2048 + lane*16 ; read2 = +1024  (both lane-linear)
    const float* pAg0 = enc + (size_t)(m0 + wid * 16 + (lane & 15)) * EDIM
                      + (lane >> 4) * 8;
    const float* pAg1 = pAg0 + 4;
    const unsigned aOff0 = (unsigned)(wid * 2048);
    const unsigned aOff1 = (unsigned)(wid * 2048 + 1024);

    // B staging: image (kt,ns) = 16KB at byte kt*32768 + ns*16384 (r10 pack).
    // Wave w copies chunk w (1KB); frag read (wn*4+j)*1024 + lane*16.
    const char* pBg = (const char*)WTp + (size_t)ns * 16384
                    + (size_t)wid * 1024 + (size_t)lane * 16;
    const unsigned bOff = (unsigned)(wid * 1024);

    f32x4 acc[4][4] = {};

    // ---- prologue: stage tile 0 ----
    GLOAD16(pAg0, ldsA[0] + aOff0);
    GLOAD16(pAg1, ldsA[0] + aOff1);
    GLOAD16(pBg,  ldsB[0] + bOff);
    __syncthreads();

    // ---- main loop ----
    for (int kt = 0; kt < NK - 1; ++kt) {
        char* aR = ldsA[kt & 1];
        char* aW = ldsA[(kt + 1) & 1];
        char* bR = ldsB[kt & 1];
        char* bW = ldsB[(kt + 1) & 1];
        // stage kt+1 (in flight until the barrier; compute covers latency)
        GLOAD16(pAg0 + (size_t)(kt + 1) * BK, aW + aOff0);
        GLOAD16(pAg1 + (size_t)(kt + 1) * BK, aW + aOff1);
        GLOAD16(pBg + (size_t)(kt + 1) * 32768, bW + bOff);
        // compute kt
        {
            short8 b[4];
            #pragma unroll
            for (int j = 0; j < 4; ++j)
                b[j] = *(const short8*)(bR + (wn * 4 + j) * 1024 + lane * 16);
            #pragma unroll
            for (int i = 0; i < 4; ++i) {
                float4 f0 = *(const float4*)(aR + (wm * 4 + i) * 2048 + lane * 16);
                float4 f1 = *(const float4*)(aR + (wm * 4 + i) * 2048 + 1024 + lane * 16);
                short8 a = cvt8(f0, f1);
                #pragma unroll
                for (int j = 0; j < 4; ++j)
                    acc[i][j] = MFMA16(a, b[j], acc[i][j]);
            }
        }
        __syncthreads();
    }
    // ---- final tile kt = NK-1 (staged in last iter -> buffer (NK-1)&1) ----
    {
        char* aR = ldsA[(NK - 1) & 1];
        char* bR = ldsB[(NK - 1) & 1];
        short8 b[4];
        #pragma unroll
        for (int j = 0; j < 4; ++j)
            b[j] = *(const short8*)(bR + (wn * 4 + j) * 1024 + lane * 16);
        #pragma unroll
        for (int i = 0; i < 4; ++i) {
            float4 f0 = *(const float4*)(aR + (wm * 4 + i) * 2048 + lane * 16);
            float4 f1 = *(const float4*)(aR + (wm * 4 + i) * 2048 + 1024 + lane * 16);
            short8 a = cvt8(f0, f1);
            #pragma unroll
            for (int j = 0; j < 4; ++j)
                acc[i][j] = MFMA16(a, b[j], acc[i][j]);
        }
    }
    __syncthreads();   // before aliasing ldsA as reduction buffer

    // ---- epilogue: relu(acc + bias) . Wfull (r12-verified 3-batch) ----
    float* red = (float*)ldsA;   // [4][256] f32 = 4 KB (aliases ldsA)
    const int bf = m0 / PIX;
    const int t1 = (bf + 1) * PIX;
    const int t2 = (bf + 2) * PIX;
    const int b1 = (bf + 1 < BATCH) ? bf + 1 : BATCH - 1;
    const int b2 = (bf + 2 < BATCH) ? bf + 2 : BATCH - 1;
    float wf[4], bs0[4], bs1[4], bs2[4];
    #pragma unroll
    for (int j = 0; j < 4; ++j) {
        int aj = ns * 256 + wn * 64 + j * 16 + cif;
        wf[j]  = Wfull[aj];
        bs0[j] = bias[(size_t)bf * ADIM + aj];
        bs1[j] = bias[(size_t)b1 * ADIM + aj];
        bs2[j] = bias[(size_t)b2 * ADIM + aj];
    }
    #pragma unroll
    for (int i = 0; i < 4; ++i) {
        #pragma unroll
        for (int rr = 0; rr < 4; ++rr) {
            int ml = wm * 64 + i * 16 + rgrp * 4 + rr;
            int m  = m0 + ml;
            float s = 0.f;
            #pragma unroll
            for (int j = 0; j < 4; ++j) {
                float bj = (m >= t2) ? bs2[j] : ((m >= t1) ? bs1[j] : bs0[j]);
                float v = acc[i][j][rr] + bj;
                s += fmaxf(v, 0.f) * wf[j];
            }
            s += __shfl_xor(s, 1);
            s += __shfl_xor(s, 2);
            s += __shfl_xor(s, 4);
            s += __shfl_xor(s, 8);
            if (cif == 0) red[wn * 256 + ml] = s;
        }
    }
    __syncthreads();
    if (tid < BM)
        att_part[(size_t)ns * MTOT + m0 + tid] =
            red[tid] + red[256 + tid] + red[512 + tid] + red[768 + tid];
}

// ---------------------------------------------------------------------------
// Kernel 3: softmax over p; att = sum of 2 N-slice partials (b_full cancels)
// ---------------------------------------------------------------------------
__global__ __launch_bounds__(256) void softmax_kernel(const float* __restrict__ att_part,
                                                      float* __restrict__ alpha) {
    const int b = blockIdx.x;
    const int tid = threadIdx.x;
    const int lane = tid & 63, wid = tid >> 6;
    __shared__ float wred[4];

    float x = -1e30f;
    if (tid < PIX) {
        size_t m = (size_t)b * PIX + tid;
        x = att_part[m] + att_part[MTOT + m];
    }
    float mx = x;
    #pragma unroll
    for (int off = 32; off >= 1; off >>= 1) mx = fmaxf(mx, __shfl_xor(mx, off));
    if (lane == 0) wred[wid] = mx;
    __syncthreads();
    float gm = fmaxf(fmaxf(wred[0], wred[1]), fmaxf(wred[2], wred[3]));
    __syncthreads();

    float e = (tid < PIX) ? __expf(x - gm) : 0.f;
    float s = e;
    #pragma unroll
    for (int off = 32; off >= 1; off >>= 1) s += __shfl_xor(s, off);
    if (lane == 0) wred[wid] = s;
    __syncthreads();
    float gs = wred[0] + wred[1] + wred[2] + wred[3];

    if (tid < PIX) alpha[(size_t)b * PIX + tid] = e / gs;
}

// ---------------------------------------------------------------------------
// Kernel 4: out[b][e] = sum_p enc[b][p][e] * alpha[b][p]
// ---------------------------------------------------------------------------
__global__ __launch_bounds__(128) void weighted_kernel(const float* __restrict__ enc,
                                                       const float* __restrict__ alpha,
                                                       float* __restrict__ out) {
    const int b = blockIdx.x >> 2;
    const int q = blockIdx.x & 3;
    const int tid = threadIdx.x;
    __shared__ float al[PIX];
    for (int i = tid; i < PIX; i += 128) al[i] = alpha[(size_t)b * PIX + i];
    __syncthreads();

    const int e = q * 512 + tid * 4;
    const float4* src = (const float4*)(enc + (size_t)b * PIX * EDIM + e);
    float ax = 0.f, ay = 0.f, az = 0.f, aw = 0.f;
    #pragma unroll 4
    for (int p = 0; p < PIX; p++) {
        float av = al[p];
        float4 v = src[(size_t)p * (EDIM / 4)];
        ax += av * v.x; ay += av * v.y; az += av * v.z; aw += av * v.w;
    }
    float4 o; o.x = ax; o.y = ay; o.z = az; o.w = aw;
    *(float4*)&out[(size_t)b * EDIM + e] = o;
}

// ---------------------------------------------------------------------------
extern "C" void kernel_launch(void* const* d_in, const int* in_sizes, int n_in,
                              void* d_out, int out_size, void* d_ws, size_t ws_size,
                              hipStream_t stream) {
    const float* enc   = (const float*)d_in[0];   // [128,196,2048]
    const float* dec   = (const float*)d_in[1];   // [128,512]
    const float* Wenc  = (const float*)d_in[2];   // [2048,512]
    const float* benc  = (const float*)d_in[3];   // [512]
    const float* Wdec  = (const float*)d_in[4];   // [512,512]
    const float* bdec  = (const float*)d_in[5];   // [512]
    const float* Wfull = (const float*)d_in[6];   // [512]
    // d_in[7] = b_full: constant shift, cancels in softmax

    float* out_awe   = (float*)d_out;                       // [128,2048]
    float* out_alpha = (float*)d_out + BATCH * EDIM;        // [128,196]

    char* ws = (char*)d_ws;
    unsigned short* WTp = (unsigned short*)ws;                      // 2 MB packed images
    float* bias = (float*)(ws + (size_t)ADIM * EDIM * 2);           // 256 KB [128][512]
    float* att_part = (float*)(ws + (size_t)ADIM * EDIM * 2
                             + (size_t)BATCH * ADIM * 4);           // 2 x 100 KB

    pack_wenc<<<NK, 256, 0, stream>>>(Wenc, WTp);
    bias_kernel<<<BATCH / 4, 256, 0, stream>>>(dec, Wdec, benc, bdec, bias);
    gemm_att<<<(MTOT / BM) * NSLC, 1024, 0, stream>>>(enc, WTp, bias, Wfull, att_part);
    softmax_kernel<<<BATCH, 256, 0, stream>>>(att_part, out_alpha);
    weighted_kernel<<<BATCH * 4, 128, 0, stream>>>(enc, out_alpha, out_awe);
}